// Round 8
// baseline (133.674 us; speedup 1.0000x reference)
//
#include <hip/hip_runtime.h>
#include <math.h>

#define IMW 512
#define IMH 512
#define NPIX (IMW * IMH)
#define C1F 1.0e-4f
#define C2F 9.0e-4f
#define NBX 8
#define NBY 16
#define NBLK (NBX * NBY * 96)
#define S0P 88     // stage0 pitch (ushorts); 176 B row stride (16-aligned, bank-spread)
#define S0PU 44    // stage0 pitch in uints
#define H2P 28     // H2 pitch (uints); j 0..23 used

typedef short s16x8 __attribute__((ext_vector_type(8)));
typedef float f32x4 __attribute__((ext_vector_type(4)));

struct Weights { float w[11]; };

__device__ __forceinline__ unsigned int bf16_rne(float f) {
    unsigned int u = __builtin_bit_cast(unsigned int, f);
    return (u + 0x7FFFu + ((u >> 16) & 1u)) >> 16;
}
__device__ __forceinline__ float bf16_to_f(unsigned int b) {
    return __builtin_bit_cast(float, b << 16);
}
__device__ __forceinline__ unsigned int pack_bf16(float a, float b) {
    return bf16_rne(a) | (bf16_rne(b) << 16);
}
__device__ __forceinline__ float wsel(const Weights& wt, int t) {
    float r = 0.f;
    #pragma unroll
    for (int k = 0; k < 11; ++k) r = (t == k) ? wt.w[k] : r;
    return r;
}

__global__ __launch_bounds__(256)
void ssim_l1_kernel(const float* __restrict__ warped,
                    const float* __restrict__ target,
                    float2* __restrict__ partial,
                    Weights wt)
{
    // stage0: 4 quantities (x, y, x^2+y^2, xy) as bf16, [q][48 rows][88 pitch]
    // after BAR2 the same memory is reused as H2: [wave][q][16 cols][28] uint (bf16 pairs)
    __shared__ unsigned int LDSU[4 * 48 * S0PU];   // 33792 B
    __shared__ float red[8];

    const int tid    = threadIdx.x;
    const int lane   = tid & 63;
    const int wv     = tid >> 6;
    const int lane15 = lane & 15;
    const int g      = lane >> 4;
    const int c0     = blockIdx.x * 64;
    const int r0     = blockIdx.y * 32;
    const size_t base = (size_t)blockIdx.z * NPIX;

    // ---- weight fragments (bf16 hi/lo split; one-time per-lane build) ----
    // h-pass B (32x16 Toeplitz): B[k][n] = w[n-k+11]; n = lane15, k = 8g+e
    // v-pass A (16x32 band):     A[i][k'] = w[k'-i];  i = lane15, k' = 8g+e
    s16x8 BwH, BwL, AvH, AvL;
    #pragma unroll
    for (int e = 0; e < 8; ++e) {
        const int k  = 8 * g + e;
        const int th = lane15 - k + 11;
        const float wh = (th >= 0 && th <= 10) ? wsel(wt, th) : 0.f;
        const int tv = k - lane15;
        const float wvv = (tv >= 0 && tv <= 10) ? wsel(wt, tv) : 0.f;
        const unsigned int h1 = bf16_rne(wh);
        const unsigned int l1 = bf16_rne(wh - bf16_to_f(h1));
        BwH[e] = (short)h1;  BwL[e] = (short)l1;
        const unsigned int h2 = bf16_rne(wvv);
        const unsigned int l2 = bf16_rne(wvv - bf16_to_f(h2));
        AvH[e] = (short)h2;  AvL[e] = (short)l2;
    }

    // ---- stage0 fill: rows slots 0..47 (rel -5..42), col slots 0..79 (rel -6..73)
    // 40 col-pairs x 48 rows = 1920 u32 px; 8 iters x 256 threads. L1 fused.
    float l1sum = 0.f;
    #pragma unroll
    for (int ii = 0; ii < 8; ++ii) {
        const int idx = tid + 256 * ii;
        if (idx < 1920) {
            const int row = idx / 40;
            const int cp  = idx - row * 40;
            const int gr  = r0 - 5 + row;
            const int gc  = c0 - 6 + 2 * cp;
            const float rm = (gr >= 0 && gr < IMH) ? 1.f : 0.f;
            const int grc = min(max(gr, 0), IMH - 1);
            const int gcc = min(max(gc, 0), IMW - 2);   // even-safe clamp
            const float2 xv = *(const float2*)(warped + base + (size_t)grc * IMW + gcc);
            const float2 yv = *(const float2*)(target + base + (size_t)grc * IMW + gcc);
            const float m0 = (gc >= 0 && gc < IMW) ? rm : 0.f;
            const float m1 = (gc + 1 < IMW) ? rm : 0.f;   // gc+1 >= 0 implied for cp>=3; left pad masked by m-formula anyway
            const float x0 = xv.x * m0, y0 = yv.x * m0;
            const float x1 = xv.y * m1, y1 = yv.y * m1;
            // L1 over output region: row slots 5..36, col-pairs 3..34
            const float lm = (row >= 5 && row <= 36 && cp >= 3 && cp <= 34) ? 1.f : 0.f;
            l1sum += lm * (fabsf(x0 - y0) + fabsf(x1 - y1));
            const unsigned int u0 = pack_bf16(x0, x1);
            const unsigned int u1 = pack_bf16(y0, y1);
            const unsigned int u2 = pack_bf16(fmaf(x0, x0, y0 * y0), fmaf(x1, x1, y1 * y1));
            const unsigned int u3 = pack_bf16(x0 * y0, x1 * y1);
            const int o = row * S0PU + cp;
            LDSU[o]                 = u0;
            LDSU[48 * S0PU + o]     = u1;
            LDSU[2 * 48 * S0PU + o] = u2;
            LDSU[3 * 48 * S0PU + o] = u3;
        }
    }
    __syncthreads();

    // ---- h-pass: 3 row-tiles x 4 quantities; C stays in registers ----
    const int cb = wv * 16;   // this wave's col-band (array-slot base of its K-window)
    const unsigned short* S = (const unsigned short*)LDSU;
    f32x4 C[4][3];
    #pragma unroll
    for (int q = 0; q < 4; ++q) {
        #pragma unroll
        for (int T = 0; T < 3; ++T) {
            const unsigned short* ap = S + (q * 48 + 16 * T + lane15) * S0P + (cb + 8 * g);
            const s16x8 A = *(const s16x8*)ap;   // ds_read_b128, 16B aligned
            f32x4 acc = {0.f, 0.f, 0.f, 0.f};
            acc = __builtin_amdgcn_mfma_f32_16x16x32_bf16(A, BwH, acc, 0, 0, 0);
            acc = __builtin_amdgcn_mfma_f32_16x16x32_bf16(A, BwL, acc, 0, 0, 0);
            C[q][T] = acc;
        }
    }
    __syncthreads();   // all stage0 reads done before H2 overwrites the same LDS

    // ---- repack C (4 rows x 1 col per lane) into H2 as bf16 pairs ----
    #pragma unroll
    for (int q = 0; q < 4; ++q) {
        #pragma unroll
        for (int T = 0; T < 3; ++T) {
            uint2 p;
            p.x = pack_bf16(C[q][T][0], C[q][T][1]);
            p.y = pack_bf16(C[q][T][2], C[q][T][3]);
            *(uint2*)&LDSU[((wv * 4 + q) * 16 + lane15) * H2P + 8 * T + 2 * g] = p;
        }
    }
    // wave-private from here: no barrier needed (compiler inserts lgkmcnt waits)

    // ---- v-pass + SSIM: 2 row-tiles, 4 quantities each ----
    float ssum = 0.f;
    #pragma unroll
    for (int rbh = 0; rbh < 2; ++rbh) {
        f32x4 V[4];
        #pragma unroll
        for (int q = 0; q < 4; ++q) {
            const uint4 br = *(const uint4*)&LDSU[((wv * 4 + q) * 16 + lane15) * H2P + 8 * rbh + 4 * g];
            const s16x8 B = __builtin_bit_cast(s16x8, br);
            f32x4 acc = {0.f, 0.f, 0.f, 0.f};
            acc = __builtin_amdgcn_mfma_f32_16x16x32_bf16(AvH, B, acc, 0, 0, 0);
            acc = __builtin_amdgcn_mfma_f32_16x16x32_bf16(AvL, B, acc, 0, 0, 0);
            V[q] = acc;
        }
        #pragma unroll
        for (int r = 0; r < 4; ++r) {
            const float mu1 = V[0][r], mu2 = V[1][r];
            const float sq  = V[2][r], sxy = V[3][r];
            const float mu1sq = mu1 * mu1;
            const float mu2sq = mu2 * mu2;
            const float mu12  = mu1 * mu2;
            const float s12   = sxy - mu12;
            const float ssig  = sq - mu1sq - mu2sq;   // sigma1^2 + sigma2^2
            const float num = (2.f * mu12 + C1F) * (2.f * s12 + C2F);
            const float den = (mu1sq + mu2sq + C1F) * (ssig + C2F);
            ssum = fmaf(num, __builtin_amdgcn_rcpf(den), ssum);
        }
    }

    // ---- reductions ----
    #pragma unroll
    for (int off = 32; off > 0; off >>= 1) {
        l1sum += __shfl_down(l1sum, off);
        ssum  += __shfl_down(ssum,  off);
    }
    if (lane == 0) { red[wv] = l1sum; red[4 + wv] = ssum; }
    __syncthreads();
    if (tid == 0) {
        const float L1 = red[0] + red[1] + red[2] + red[3];
        const float SS = red[4] + red[5] + red[6] + red[7];
        const int bid = (blockIdx.z * gridDim.y + blockIdx.y) * gridDim.x + blockIdx.x;
        partial[bid] = make_float2(L1, SS);
    }
}

__global__ __launch_bounds__(256)
void reduce_kernel(const float2* __restrict__ partial, float* __restrict__ out)
{
    double l1 = 0.0, ss = 0.0;
    for (int i = threadIdx.x; i < NBLK; i += 256) {
        const float2 p = partial[i];
        l1 += (double)p.x;
        ss += (double)p.y;
    }
    #pragma unroll
    for (int off = 32; off > 0; off >>= 1) {
        l1 += __shfl_down(l1, off);
        ss += __shfl_down(ss, off);
    }
    __shared__ double red[8];
    const int wv = threadIdx.x >> 6, lane = threadIdx.x & 63;
    if (lane == 0) { red[wv] = l1; red[4 + wv] = ss; }
    __syncthreads();
    if (threadIdx.x == 0) {
        const double n = 25165824.0;   // 32*3*512*512
        const double L1 = (red[0] + red[1] + red[2] + red[3]) / n;
        const double SS = (red[4] + red[5] + red[6] + red[7]) / n;
        out[0] = (float)(0.5 * L1 + 0.5 * (1.0 - SS));
    }
}

extern "C" void kernel_launch(void* const* d_in, const int* in_sizes, int n_in,
                              void* d_out, int out_size, void* d_ws, size_t ws_size,
                              hipStream_t stream)
{
    const float* warped = (const float*)d_in[0];
    const float* target = (const float*)d_in[1];
    float* out      = (float*)d_out;
    float2* partial = (float2*)d_ws;

    // Gaussian window (f32, same as reference)
    Weights wt;
    float gg[11], sum = 0.0f;
    for (int i = 0; i < 11; ++i) {
        const float cc = (float)(i - 5);
        gg[i] = expf(-(cc * cc) / (2.0f * 1.5f * 1.5f));
        sum += gg[i];
    }
    for (int i = 0; i < 11; ++i) wt.w[i] = gg[i] / sum;

    dim3 grid(NBX, NBY, 96);   // 64-col tiles x 32-row tiles x planes
    dim3 block(256);
    hipLaunchKernelGGL(ssim_l1_kernel, grid, block, 0, stream,
                       warped, target, partial, wt);
    hipLaunchKernelGGL(reduce_kernel, dim3(1), dim3(256), 0, stream, partial, out);
}

// Round 9
// 102.806 us; speedup vs baseline: 1.3003x; 1.3003x over previous
//
#include <hip/hip_runtime.h>
#include <math.h>

#define IMW 512
#define IMH 512
#define NPIX (IMW * IMH)
#define NBX 8
#define NBY 16
#define NBLK (NBX * NBY * 96)
#define C1F 1.0e-4f
#define C2F 9.0e-4f
#define H2P 28

typedef short s16x8 __attribute__((ext_vector_type(8)));
typedef float f32x4 __attribute__((ext_vector_type(4)));

// ---- helpers ----
__device__ __forceinline__ unsigned cvtpk(float a, float b) {   // lo=bf16(a), hi=bf16(b), RNE
    unsigned r;
    asm("v_cvt_pk_bf16_f32 %0, %1, %2" : "=v"(r) : "v"(a), "v"(b));
    return r;
}
__device__ __forceinline__ unsigned bf16_rne(float f) {
    unsigned u = __builtin_bit_cast(unsigned, f);
    return (u + 0x7FFFu + ((u >> 16) & 1u)) >> 16;
}
__device__ __forceinline__ float bf16_to_f(unsigned b) {
    return __builtin_bit_cast(float, b << 16);
}
__device__ __forceinline__ void gload16(const float* g, void* l) {
    __builtin_amdgcn_global_load_lds(
        (const __attribute__((address_space(1))) void*)g,
        (__attribute__((address_space(3))) void*)l,
        16, 0, 0);
}

// ---- setup: build per-lane MFMA weight fragments once (block-invariant) ----
__global__ void setup_kernel(uint4* __restrict__ wtab)
{
    const int lane = threadIdx.x;        // 0..63
    const int lane15 = lane & 15;
    const int g = lane >> 4;
    float w[11];
    float s = 0.f;
    for (int i = 0; i < 11; ++i) {
        const float c = (float)(i - 5);
        w[i] = expf(-(c * c) / 4.5f);
        s += w[i];
    }
    for (int i = 0; i < 11; ++i) w[i] /= s;

    s16x8 bwh, bwl, avh, avl;
    #pragma unroll
    for (int e = 0; e < 8; ++e) {
        const int k = 8 * g + e;
        // h-pass B (32x16): B[k][n] = w[k-n-3]  (slot origin c0-8; out col n = c0+16wv+n)
        const int th = k - lane15 - 3;
        const float wh = (th >= 0 && th <= 10) ? w[th] : 0.f;
        // v-pass A (16x32): A[i][k'] = w[k'-i]
        const int tv = k - lane15;
        const float wvv = (tv >= 0 && tv <= 10) ? w[tv] : 0.f;
        const unsigned h1 = bf16_rne(wh);
        const unsigned l1 = bf16_rne(wh - bf16_to_f(h1));
        bwh[e] = (short)h1; bwl[e] = (short)l1;
        const unsigned h2 = bf16_rne(wvv);
        const unsigned l2 = bf16_rne(wvv - bf16_to_f(h2));
        avh[e] = (short)h2; avl[e] = (short)l2;
    }
    wtab[lane * 4 + 0] = __builtin_bit_cast(uint4, bwh);
    wtab[lane * 4 + 1] = __builtin_bit_cast(uint4, bwl);
    wtab[lane * 4 + 2] = __builtin_bit_cast(uint4, avh);
    wtab[lane * 4 + 3] = __builtin_bit_cast(uint4, avl);
}

__global__ __launch_bounds__(256)
void ssim_l1_kernel(const float* __restrict__ warped,
                    const float* __restrict__ target,
                    const uint4* __restrict__ wtab,
                    float2* __restrict__ partial)
{
    // staging: x rows 0..47 at bytes [0, 24576), y at [24576, 49152); pitch 512 B (128 f32)
    // swizzle: byte-in-row ^= (row&7)<<4 (16B granules); after barrier2 bytes [0,28672) reused as H2
    __shared__ unsigned int LDSU[12296];   // 49152 B + 8-float red tail

    const int tid = threadIdx.x;
    const int lane = tid & 63;
    const int wv = tid >> 6;
    const int lane15 = lane & 15;
    const int g = lane >> 4;
    const int c0 = blockIdx.x * 64;
    const int r0 = blockIdx.y * 32;
    const size_t base = (size_t)blockIdx.z * NPIX;
    char* LB = (char*)LDSU;

    // ---- load weight fragments (L2-resident 4KB table) ----
    const s16x8 BwH = __builtin_bit_cast(s16x8, wtab[lane * 4 + 0]);
    const s16x8 BwL = __builtin_bit_cast(s16x8, wtab[lane * 4 + 1]);
    const s16x8 AvH = __builtin_bit_cast(s16x8, wtab[lane * 4 + 2]);
    const s16x8 AvL = __builtin_bit_cast(s16x8, wtab[lane * 4 + 3]);

    // ---- stage raw x,y ----
    const bool xedge = (blockIdx.x == 0) || (blockIdx.x == NBX - 1);
    if (!xedge) {
        // async HBM->LDS, zero VALU per element; source pre-swizzled, dest linear
        const int half = lane >> 5;
        const int l31 = lane & 31;
        #pragma unroll
        for (int c = wv; c < 24; c += 4) {          // 2 rows per 1024B chunk
            const int row = 2 * c + half;
            const int rimg = min(max(r0 - 5 + row, 0), IMH - 1);  // clamped; by-edges zero-filled below
            const unsigned sb = ((unsigned)(l31 * 16)) ^ ((unsigned)((row & 7) << 4));
            const float* gx = warped + base + (size_t)rimg * IMW + (c0 - 8) + (sb >> 2);
            const float* gy = target + base + (size_t)rimg * IMW + (c0 - 8) + (sb >> 2);
            gload16(gx, LB + c * 1024);
            gload16(gy, LB + 24576 + c * 1024);
        }
    } else {
        // masked VALU path (bx 0,7 only): stage slots 0..79 (all the h-pass reads)
        #pragma unroll
        for (int ii = 0; ii < 15; ++ii) {
            const int idx = tid + 256 * ii;          // < 3840 = 48 rows * 80 slots
            const int row = idx / 80;
            const int j = idx - row * 80;
            const int gr = r0 - 5 + row;
            const int gc = c0 - 8 + j;
            const bool ok = (gr >= 0) && (gr < IMH) && (gc >= 0) && (gc < IMW);
            const int grc = min(max(gr, 0), IMH - 1);
            const int gcc = min(max(gc, 0), IMW - 1);
            float xv = warped[base + (size_t)grc * IMW + gcc];
            float yv = target[base + (size_t)grc * IMW + gcc];
            xv = ok ? xv : 0.f;
            yv = ok ? yv : 0.f;
            const unsigned b = (unsigned)(row * 512) +
                               (((unsigned)(4 * j)) ^ ((unsigned)((row & 7) << 4)));
            *(float*)(LB + b) = xv;
            *(float*)(LB + 24576 + b) = yv;
        }
    }
    __syncthreads();   // drains gload vmcnt + ds writes

    // ---- zero-pad out-of-image rows (zero rows are swizzle-invariant) ----
    if (blockIdx.y == 0) {
        #pragma unroll
        for (int k = tid; k < 1280; k += 256)
            LDSU[(k < 640) ? k : (6144 + k - 640)] = 0u;           // rows 0..4, x then y
    }
    if (blockIdx.y == NBY - 1) {
        #pragma unroll
        for (int k = tid; k < 1280; k += 256)
            LDSU[(k < 640) ? (5504 + k) : (6144 + 5504 + k - 640)] = 0u;  // rows 43..47
    }
    __syncthreads();

    // ---- L1 column weights: count each output col exactly once across overlapped windows ----
    float colw[8];
    #pragma unroll
    for (int e = 0; e < 8; ++e) {
        const int s = 16 * wv + 8 * g + e;           // staging slot; out cols = slots 8..71
        colw[e] = (s < 8 || s > 71) ? 0.f : ((s < 16 || s >= 64) ? 1.f : 0.5f);
    }

    float l1sum = 0.f;
    f32x4 C[4][3];
    #pragma unroll
    for (int q = 0; q < 4; ++q)
        #pragma unroll
        for (int T = 0; T < 3; ++T)
            C[q][T] = {0.f, 0.f, 0.f, 0.f};

    // ---- h-pass: read raw f32, build bf16 fragments (cvt_pk) + products in-reg, MFMA ----
    const unsigned wb = (unsigned)((16 * wv + 8 * g) * 4);   // 16B-aligned window base
    #pragma unroll
    for (int T = 0; T < 3; ++T) {
        const int rs = 16 * T + lane15;
        const unsigned rb = (unsigned)(rs * 512);
        const unsigned swz = (unsigned)((rs & 7) << 4);
        const f32x4 x0 = *(const f32x4*)(LB + rb + (wb ^ swz));
        const f32x4 x1 = *(const f32x4*)(LB + rb + ((wb + 16) ^ swz));
        const f32x4 y0 = *(const f32x4*)(LB + 24576 + rb + (wb ^ swz));
        const f32x4 y1 = *(const f32x4*)(LB + 24576 + rb + ((wb + 16) ^ swz));

        // L1 (exact f32, exact single coverage; rows slots 5..36 = output rows)
        {
            const float rm = (T == 0) ? ((lane15 >= 5) ? 1.f : 0.f)
                           : (T == 1) ? 1.f
                           : ((lane15 <= 4) ? 1.f : 0.f);
            float acc = 0.f;
            #pragma unroll
            for (int e = 0; e < 4; ++e) acc = fmaf(colw[e], fabsf(x0[e] - y0[e]), acc);
            #pragma unroll
            for (int e = 0; e < 4; ++e) acc = fmaf(colw[4 + e], fabsf(x1[e] - y1[e]), acc);
            l1sum = fmaf(rm, acc, l1sum);
        }

        uint4 A0u, A1u, A2u, A3u;
        A0u.x = cvtpk(x0[0], x0[1]); A0u.y = cvtpk(x0[2], x0[3]);
        A0u.z = cvtpk(x1[0], x1[1]); A0u.w = cvtpk(x1[2], x1[3]);
        A1u.x = cvtpk(y0[0], y0[1]); A1u.y = cvtpk(y0[2], y0[3]);
        A1u.z = cvtpk(y1[0], y1[1]); A1u.w = cvtpk(y1[2], y1[3]);
        A2u.x = cvtpk(fmaf(x0[0], x0[0], y0[0] * y0[0]), fmaf(x0[1], x0[1], y0[1] * y0[1]));
        A2u.y = cvtpk(fmaf(x0[2], x0[2], y0[2] * y0[2]), fmaf(x0[3], x0[3], y0[3] * y0[3]));
        A2u.z = cvtpk(fmaf(x1[0], x1[0], y1[0] * y1[0]), fmaf(x1[1], x1[1], y1[1] * y1[1]));
        A2u.w = cvtpk(fmaf(x1[2], x1[2], y1[2] * y1[2]), fmaf(x1[3], x1[3], y1[3] * y1[3]));
        A3u.x = cvtpk(x0[0] * y0[0], x0[1] * y0[1]);
        A3u.y = cvtpk(x0[2] * y0[2], x0[3] * y0[3]);
        A3u.z = cvtpk(x1[0] * y1[0], x1[1] * y1[1]);
        A3u.w = cvtpk(x1[2] * y1[2], x1[3] * y1[3]);

        const s16x8 A0 = __builtin_bit_cast(s16x8, A0u);
        const s16x8 A1 = __builtin_bit_cast(s16x8, A1u);
        const s16x8 A2 = __builtin_bit_cast(s16x8, A2u);
        const s16x8 A3 = __builtin_bit_cast(s16x8, A3u);

        C[0][T] = __builtin_amdgcn_mfma_f32_16x16x32_bf16(A0, BwH, C[0][T], 0, 0, 0);
        C[0][T] = __builtin_amdgcn_mfma_f32_16x16x32_bf16(A0, BwL, C[0][T], 0, 0, 0);
        C[1][T] = __builtin_amdgcn_mfma_f32_16x16x32_bf16(A1, BwH, C[1][T], 0, 0, 0);
        C[1][T] = __builtin_amdgcn_mfma_f32_16x16x32_bf16(A1, BwL, C[1][T], 0, 0, 0);
        C[2][T] = __builtin_amdgcn_mfma_f32_16x16x32_bf16(A2, BwH, C[2][T], 0, 0, 0);
        C[2][T] = __builtin_amdgcn_mfma_f32_16x16x32_bf16(A2, BwL, C[2][T], 0, 0, 0);
        C[3][T] = __builtin_amdgcn_mfma_f32_16x16x32_bf16(A3, BwH, C[3][T], 0, 0, 0);
        C[3][T] = __builtin_amdgcn_mfma_f32_16x16x32_bf16(A3, BwL, C[3][T], 0, 0, 0);
    }
    __syncthreads();   // all staging reads done before H2 overwrites the region

    // ---- repack C into H2 (wave-private band; bf16 pairs) ----
    #pragma unroll
    for (int q = 0; q < 4; ++q) {
        #pragma unroll
        for (int T = 0; T < 3; ++T) {
            uint2 p;
            p.x = cvtpk(C[q][T][0], C[q][T][1]);
            p.y = cvtpk(C[q][T][2], C[q][T][3]);
            *(uint2*)&LDSU[((wv * 4 + q) * 16 + lane15) * H2P + 8 * T + 2 * g] = p;
        }
    }

    // ---- v-pass + SSIM ----
    float ssum = 0.f;
    #pragma unroll
    for (int rbh = 0; rbh < 2; ++rbh) {
        f32x4 V[4];
        #pragma unroll
        for (int q = 0; q < 4; ++q) {
            const uint4 br = *(const uint4*)&LDSU[((wv * 4 + q) * 16 + lane15) * H2P + 8 * rbh + 4 * g];
            const s16x8 B = __builtin_bit_cast(s16x8, br);
            f32x4 acc = {0.f, 0.f, 0.f, 0.f};
            acc = __builtin_amdgcn_mfma_f32_16x16x32_bf16(AvH, B, acc, 0, 0, 0);
            acc = __builtin_amdgcn_mfma_f32_16x16x32_bf16(AvL, B, acc, 0, 0, 0);
            V[q] = acc;
        }
        #pragma unroll
        for (int r = 0; r < 4; ++r) {
            const float mu1 = V[0][r], mu2 = V[1][r];
            const float sq  = V[2][r], sxy = V[3][r];
            const float mu1sq = mu1 * mu1;
            const float mu2sq = mu2 * mu2;
            const float mu12  = mu1 * mu2;
            const float s12   = sxy - mu12;
            const float ssig  = sq - mu1sq - mu2sq;   // sigma1^2 + sigma2^2
            const float num = (2.f * mu12 + C1F) * (2.f * s12 + C2F);
            const float den = (mu1sq + mu2sq + C1F) * (ssig + C2F);
            ssum = fmaf(num, __builtin_amdgcn_rcpf(den), ssum);
        }
    }

    // ---- reductions ----
    #pragma unroll
    for (int off = 32; off > 0; off >>= 1) {
        l1sum += __shfl_down(l1sum, off);
        ssum  += __shfl_down(ssum,  off);
    }
    float* red = (float*)&LDSU[12288];
    if (lane == 0) { red[wv] = l1sum; red[4 + wv] = ssum; }
    __syncthreads();
    if (tid == 0) {
        const float L1 = red[0] + red[1] + red[2] + red[3];
        const float SS = red[4] + red[5] + red[6] + red[7];
        const int bid = (blockIdx.z * gridDim.y + blockIdx.y) * gridDim.x + blockIdx.x;
        partial[bid] = make_float2(L1, SS);
    }
}

__global__ __launch_bounds__(256)
void reduce_kernel(const float2* __restrict__ partial, float* __restrict__ out)
{
    double l1 = 0.0, ss = 0.0;
    for (int i = threadIdx.x; i < NBLK; i += 256) {
        const float2 p = partial[i];
        l1 += (double)p.x;
        ss += (double)p.y;
    }
    #pragma unroll
    for (int off = 32; off > 0; off >>= 1) {
        l1 += __shfl_down(l1, off);
        ss += __shfl_down(ss, off);
    }
    __shared__ double red[8];
    const int wv = threadIdx.x >> 6, lane = threadIdx.x & 63;
    if (lane == 0) { red[wv] = l1; red[4 + wv] = ss; }
    __syncthreads();
    if (threadIdx.x == 0) {
        const double n = 25165824.0;   // 32*3*512*512
        const double L1 = (red[0] + red[1] + red[2] + red[3]) / n;
        const double SS = (red[4] + red[5] + red[6] + red[7]) / n;
        out[0] = (float)(0.5 * L1 + 0.5 * (1.0 - SS));
    }
}

extern "C" void kernel_launch(void* const* d_in, const int* in_sizes, int n_in,
                              void* d_out, int out_size, void* d_ws, size_t ws_size,
                              hipStream_t stream)
{
    const float* warped = (const float*)d_in[0];
    const float* target = (const float*)d_in[1];
    float* out = (float*)d_out;
    uint4* wtab = (uint4*)d_ws;                            // 4 KB fragment table
    float2* partial = (float2*)((char*)d_ws + 4096);       // NBLK float2 partials

    hipLaunchKernelGGL(setup_kernel, dim3(1), dim3(64), 0, stream, wtab);
    hipLaunchKernelGGL(ssim_l1_kernel, dim3(NBX, NBY, 96), dim3(256), 0, stream,
                       warped, target, wtab, partial);
    hipLaunchKernelGGL(reduce_kernel, dim3(1), dim3(256), 0, stream, partial, out);
}

// Round 10
// 87.422 us; speedup vs baseline: 1.5291x; 1.1760x over previous
//
#include <hip/hip_runtime.h>
#include <math.h>

#define IMW 512
#define IMH 512
#define NPIX (IMW * IMH)
#define NBX 8
#define NBY 16
#define NBLK (NBX * NBY * 96)
#define C1F 1.0e-4f
#define C2F 9.0e-4f
#define H2P 28
#define S0W 96          // staged row pitch in words (384 B)
#define YW  4608        // y-field word offset (48 rows * 96)

typedef short s16x8 __attribute__((ext_vector_type(8)));
typedef float f32x4 __attribute__((ext_vector_type(4)));

// ---- helpers ----
__device__ __forceinline__ unsigned cvtpk(float a, float b) {   // lo=bf16(a), hi=bf16(b), RNE
    unsigned r;
    asm("v_cvt_pk_bf16_f32 %0, %1, %2" : "=v"(r) : "v"(a), "v"(b));
    return r;
}
__device__ __forceinline__ unsigned bf16_rne(float f) {
    unsigned u = __builtin_bit_cast(unsigned, f);
    return (u + 0x7FFFu + ((u >> 16) & 1u)) >> 16;
}
__device__ __forceinline__ float bf16_to_f(unsigned b) {
    return __builtin_bit_cast(float, b << 16);
}
__device__ __forceinline__ void gload16(const void* g, void* l) {
    __builtin_amdgcn_global_load_lds(
        (const __attribute__((address_space(1))) void*)g,
        (__attribute__((address_space(3))) void*)l,
        16, 0, 0);
}

// ---- setup: build per-lane MFMA weight fragments once (block-invariant) ----
__global__ void setup_kernel(uint4* __restrict__ wtab)
{
    const int lane = threadIdx.x;        // 0..63
    const int lane15 = lane & 15;
    const int g = lane >> 4;
    float w[11];
    float s = 0.f;
    for (int i = 0; i < 11; ++i) {
        const float c = (float)(i - 5);
        w[i] = expf(-(c * c) / 4.5f);
        s += w[i];
    }
    for (int i = 0; i < 11; ++i) w[i] /= s;

    s16x8 bwh, bwl, avh, avl;
    #pragma unroll
    for (int e = 0; e < 8; ++e) {
        const int k = 8 * g + e;
        // h-pass B (32x16): B[k][n] = w[k-n-3]  (slot origin c0-8; out col n = c0+16wv+n)
        const int th = k - lane15 - 3;
        const float wh = (th >= 0 && th <= 10) ? w[th] : 0.f;
        // v-pass A (16x32): A[i][k'] = w[k'-i]
        const int tv = k - lane15;
        const float wvv = (tv >= 0 && tv <= 10) ? w[tv] : 0.f;
        const unsigned h1 = bf16_rne(wh);
        const unsigned l1 = bf16_rne(wh - bf16_to_f(h1));
        bwh[e] = (short)h1; bwl[e] = (short)l1;
        const unsigned h2 = bf16_rne(wvv);
        const unsigned l2 = bf16_rne(wvv - bf16_to_f(h2));
        avh[e] = (short)h2; avl[e] = (short)l2;
    }
    wtab[lane * 4 + 0] = __builtin_bit_cast(uint4, bwh);
    wtab[lane * 4 + 1] = __builtin_bit_cast(uint4, bwl);
    wtab[lane * 4 + 2] = __builtin_bit_cast(uint4, avh);
    wtab[lane * 4 + 3] = __builtin_bit_cast(uint4, avl);
}

__global__ __launch_bounds__(256)
void ssim_l1_kernel(const float* __restrict__ warped,
                    const float* __restrict__ target,
                    const uint4* __restrict__ wtab,
                    float2* __restrict__ partial)
{
    // staging: x rows 0..47 words [0, 4608), y words [4608, 9216); pitch 96 words (384 B)
    // swizzle: 16B granule-in-row ^= (row & 7); after barrier2 words [0, 7168) reused as H2
    __shared__ unsigned int LDSU[9224];   // 36864 B staging + 32 B red tail

    const int tid = threadIdx.x;
    const int lane = tid & 63;
    const int wv = tid >> 6;
    const int lane15 = lane & 15;
    const int g = tid >> 4 & 3;
    const int c0 = blockIdx.x * 64;
    const int r0 = blockIdx.y * 32;
    const size_t base = (size_t)blockIdx.z * NPIX;
    char* LB = (char*)LDSU;

    // ---- stage raw x,y via async gload; per-lane clamped+swizzled source ----
    {
        const char* xrow = (const char*)(warped + base);
        const char* yrow = (const char*)(target + base);
        const int cb0 = (c0 - 8) * 4;                 // byte offset of slot 0 in row
        #pragma unroll
        for (int i = 0; i < 5; ++i) {
            const int ck = wv + 4 * i;                // 1KB chunk 0..17
            if (ck < 18) {
                const unsigned off = 1024u * (unsigned)ck + 16u * (unsigned)lane;
                const unsigned q = off >> 7;
                const unsigned row = (q * 171u) >> 9;          // off / 384, exact
                const unsigned rem = off - 384u * row;
                const unsigned gl = rem >> 4;                  // LDS granule 0..23
                const unsigned gs = gl ^ (row & 7u);           // source granule (XOR involution)
                const int srow = min(max(r0 - 5 + (int)row, 0), IMH - 1);
                const int scolb = min(max(cb0 + (int)(gs << 4), 0), 2032);
                const size_t rb = (size_t)srow * (IMW * 4);
                gload16(xrow + rb + scolb, LB + 1024 * ck);
                gload16(yrow + rb + scolb, LB + 18432 + 1024 * ck);
            }
        }
    }
    // ---- load weight fragments (L2-resident 4KB table) while loads fly ----
    const s16x8 BwH = __builtin_bit_cast(s16x8, wtab[lane * 4 + 0]);
    const s16x8 BwL = __builtin_bit_cast(s16x8, wtab[lane * 4 + 1]);
    const s16x8 AvH = __builtin_bit_cast(s16x8, wtab[lane * 4 + 2]);
    const s16x8 AvL = __builtin_bit_cast(s16x8, wtab[lane * 4 + 3]);

    __syncthreads();   // drains gload vmcnt

    // ---- zero-pad out-of-image rows (zero rows are swizzle-invariant) ----
    if (blockIdx.y == 0) {
        #pragma unroll
        for (int k = tid; k < 960; k += 256)        // rows 0..4, x then y
            LDSU[(k < 480) ? k : (YW + k - 480)] = 0u;
    }
    if (blockIdx.y == NBY - 1) {
        #pragma unroll
        for (int k = tid; k < 960; k += 256)        // rows 43..47
            LDSU[(k < 480) ? (4128 + k) : (YW + 4128 + k - 480)] = 0u;
    }
    __syncthreads();

    // ---- L1 column weights (exact single coverage of overlapped windows) ----
    const int s0 = 16 * wv + 8 * g;                 // first staging slot of this lane
    float colw[8];
    #pragma unroll
    for (int e = 0; e < 8; ++e) {
        const int s = s0 + e;
        colw[e] = (s < 8 || s > 71) ? 0.f : ((s < 16 || s >= 64) ? 1.f : 0.5f);
    }
    // x-edge masks (zero out-of-image slots before MFMA)
    const bool xedge = (blockIdx.x == 0) || (blockIdx.x == NBX - 1);
    f32x4 mx0, mx1;
    #pragma unroll
    for (int e = 0; e < 4; ++e) {
        const int cA = c0 - 8 + s0 + e;
        const int cB = cA + 4;
        mx0[e] = (cA >= 0 && cA < IMW) ? 1.f : 0.f;
        mx1[e] = (cB >= 0 && cB < IMW) ? 1.f : 0.f;
    }

    float l1sum = 0.f;
    f32x4 C[4][3];
    #pragma unroll
    for (int q = 0; q < 4; ++q)
        #pragma unroll
        for (int T = 0; T < 3; ++T)
            C[q][T] = {0.f, 0.f, 0.f, 0.f};

    // ---- h-pass: read raw f32, build bf16 fragments + products in-reg, MFMA ----
    const unsigned wb = (unsigned)(s0 * 4);         // byte offset in row (32B-aligned)
    #pragma unroll
    for (int T = 0; T < 3; ++T) {
        const int rs = 16 * T + lane15;
        const unsigned rb = (unsigned)(rs * 384);
        const unsigned swz = (unsigned)((rs & 7) << 4);
        f32x4 x0 = *(const f32x4*)(LB + rb + (wb ^ swz));
        f32x4 x1 = *(const f32x4*)(LB + rb + ((wb + 16) ^ swz));
        f32x4 y0 = *(const f32x4*)(LB + 18432 + rb + (wb ^ swz));
        f32x4 y1 = *(const f32x4*)(LB + 18432 + rb + ((wb + 16) ^ swz));
        if (xedge) {
            x0 *= mx0; x1 *= mx1; y0 *= mx0; y1 *= mx1;
        }

        // L1 (exact f32; rows slots 5..36 are output rows)
        {
            const float rm = (T == 0) ? ((lane15 >= 5) ? 1.f : 0.f)
                           : (T == 1) ? 1.f
                           : ((lane15 <= 4) ? 1.f : 0.f);
            float acc = 0.f;
            #pragma unroll
            for (int e = 0; e < 4; ++e) acc = fmaf(colw[e], fabsf(x0[e] - y0[e]), acc);
            #pragma unroll
            for (int e = 0; e < 4; ++e) acc = fmaf(colw[4 + e], fabsf(x1[e] - y1[e]), acc);
            l1sum = fmaf(rm, acc, l1sum);
        }

        uint4 A0u, A1u, A2u, A3u;
        A0u.x = cvtpk(x0[0], x0[1]); A0u.y = cvtpk(x0[2], x0[3]);
        A0u.z = cvtpk(x1[0], x1[1]); A0u.w = cvtpk(x1[2], x1[3]);
        A1u.x = cvtpk(y0[0], y0[1]); A1u.y = cvtpk(y0[2], y0[3]);
        A1u.z = cvtpk(y1[0], y1[1]); A1u.w = cvtpk(y1[2], y1[3]);
        A2u.x = cvtpk(fmaf(x0[0], x0[0], y0[0] * y0[0]), fmaf(x0[1], x0[1], y0[1] * y0[1]));
        A2u.y = cvtpk(fmaf(x0[2], x0[2], y0[2] * y0[2]), fmaf(x0[3], x0[3], y0[3] * y0[3]));
        A2u.z = cvtpk(fmaf(x1[0], x1[0], y1[0] * y1[0]), fmaf(x1[1], x1[1], y1[1] * y1[1]));
        A2u.w = cvtpk(fmaf(x1[2], x1[2], y1[2] * y1[2]), fmaf(x1[3], x1[3], y1[3] * y1[3]));
        A3u.x = cvtpk(x0[0] * y0[0], x0[1] * y0[1]);
        A3u.y = cvtpk(x0[2] * y0[2], x0[3] * y0[3]);
        A3u.z = cvtpk(x1[0] * y1[0], x1[1] * y1[1]);
        A3u.w = cvtpk(x1[2] * y1[2], x1[3] * y1[3]);

        const s16x8 A0 = __builtin_bit_cast(s16x8, A0u);
        const s16x8 A1 = __builtin_bit_cast(s16x8, A1u);
        const s16x8 A2 = __builtin_bit_cast(s16x8, A2u);
        const s16x8 A3 = __builtin_bit_cast(s16x8, A3u);

        C[0][T] = __builtin_amdgcn_mfma_f32_16x16x32_bf16(A0, BwH, C[0][T], 0, 0, 0);
        C[0][T] = __builtin_amdgcn_mfma_f32_16x16x32_bf16(A0, BwL, C[0][T], 0, 0, 0);
        C[1][T] = __builtin_amdgcn_mfma_f32_16x16x32_bf16(A1, BwH, C[1][T], 0, 0, 0);
        C[1][T] = __builtin_amdgcn_mfma_f32_16x16x32_bf16(A1, BwL, C[1][T], 0, 0, 0);
        C[2][T] = __builtin_amdgcn_mfma_f32_16x16x32_bf16(A2, BwH, C[2][T], 0, 0, 0);
        C[2][T] = __builtin_amdgcn_mfma_f32_16x16x32_bf16(A2, BwL, C[2][T], 0, 0, 0);
        C[3][T] = __builtin_amdgcn_mfma_f32_16x16x32_bf16(A3, BwH, C[3][T], 0, 0, 0);
        C[3][T] = __builtin_amdgcn_mfma_f32_16x16x32_bf16(A3, BwL, C[3][T], 0, 0, 0);
    }
    __syncthreads();   // all staging reads done before H2 overwrites the region

    // ---- repack C into H2 (wave-private band; bf16 pairs) ----
    #pragma unroll
    for (int q = 0; q < 4; ++q) {
        #pragma unroll
        for (int T = 0; T < 3; ++T) {
            uint2 p;
            p.x = cvtpk(C[q][T][0], C[q][T][1]);
            p.y = cvtpk(C[q][T][2], C[q][T][3]);
            *(uint2*)&LDSU[((wv * 4 + q) * 16 + lane15) * H2P + 8 * T + 2 * g] = p;
        }
    }

    // ---- v-pass + SSIM ----
    float ssum = 0.f;
    #pragma unroll
    for (int rbh = 0; rbh < 2; ++rbh) {
        f32x4 V[4];
        #pragma unroll
        for (int q = 0; q < 4; ++q) {
            const uint4 br = *(const uint4*)&LDSU[((wv * 4 + q) * 16 + lane15) * H2P + 8 * rbh + 4 * g];
            const s16x8 B = __builtin_bit_cast(s16x8, br);
            f32x4 acc = {0.f, 0.f, 0.f, 0.f};
            acc = __builtin_amdgcn_mfma_f32_16x16x32_bf16(AvH, B, acc, 0, 0, 0);
            acc = __builtin_amdgcn_mfma_f32_16x16x32_bf16(AvL, B, acc, 0, 0, 0);
            V[q] = acc;
        }
        #pragma unroll
        for (int r = 0; r < 4; ++r) {
            const float mu1 = V[0][r], mu2 = V[1][r];
            const float sq  = V[2][r], sxy = V[3][r];
            const float mu1sq = mu1 * mu1;
            const float mu2sq = mu2 * mu2;
            const float mu12  = mu1 * mu2;
            const float s12   = sxy - mu12;
            const float ssig  = sq - mu1sq - mu2sq;   // sigma1^2 + sigma2^2
            const float num = (2.f * mu12 + C1F) * (2.f * s12 + C2F);
            const float den = (mu1sq + mu2sq + C1F) * (ssig + C2F);
            ssum = fmaf(num, __builtin_amdgcn_rcpf(den), ssum);
        }
    }

    // ---- reductions ----
    #pragma unroll
    for (int off = 32; off > 0; off >>= 1) {
        l1sum += __shfl_down(l1sum, off);
        ssum  += __shfl_down(ssum,  off);
    }
    float* red = (float*)&LDSU[9216];
    if (lane == 0) { red[wv] = l1sum; red[4 + wv] = ssum; }
    __syncthreads();
    if (tid == 0) {
        const float L1 = red[0] + red[1] + red[2] + red[3];
        const float SS = red[4] + red[5] + red[6] + red[7];
        const int bid = (blockIdx.z * gridDim.y + blockIdx.y) * gridDim.x + blockIdx.x;
        partial[bid] = make_float2(L1, SS);
    }
}

__global__ __launch_bounds__(256)
void reduce_kernel(const float2* __restrict__ partial, float* __restrict__ out)
{
    double l1 = 0.0, ss = 0.0;
    for (int i = threadIdx.x; i < NBLK; i += 256) {
        const float2 p = partial[i];
        l1 += (double)p.x;
        ss += (double)p.y;
    }
    #pragma unroll
    for (int off = 32; off > 0; off >>= 1) {
        l1 += __shfl_down(l1, off);
        ss += __shfl_down(ss, off);
    }
    __shared__ double red[8];
    const int wv = threadIdx.x >> 6, lane = threadIdx.x & 63;
    if (lane == 0) { red[wv] = l1; red[4 + wv] = ss; }
    __syncthreads();
    if (threadIdx.x == 0) {
        const double n = 25165824.0;   // 32*3*512*512
        const double L1 = (red[0] + red[1] + red[2] + red[3]) / n;
        const double SS = (red[4] + red[5] + red[6] + red[7]) / n;
        out[0] = (float)(0.5 * L1 + 0.5 * (1.0 - SS));
    }
}

extern "C" void kernel_launch(void* const* d_in, const int* in_sizes, int n_in,
                              void* d_out, int out_size, void* d_ws, size_t ws_size,
                              hipStream_t stream)
{
    const float* warped = (const float*)d_in[0];
    const float* target = (const float*)d_in[1];
    float* out = (float*)d_out;
    uint4* wtab = (uint4*)d_ws;                            // 4 KB fragment table
    float2* partial = (float2*)((char*)d_ws + 4096);       // NBLK float2 partials

    hipLaunchKernelGGL(setup_kernel, dim3(1), dim3(64), 0, stream, wtab);
    hipLaunchKernelGGL(ssim_l1_kernel, dim3(NBX, NBY, 96), dim3(256), 0, stream,
                       warped, target, wtab, partial);
    hipLaunchKernelGGL(reduce_kernel, dim3(1), dim3(256), 0, stream, partial, out);
}

// Round 11
// 84.296 us; speedup vs baseline: 1.5858x; 1.0371x over previous
//
#include <hip/hip_runtime.h>
#include <math.h>

#define IMW 512
#define IMH 512
#define NPIX (IMW * IMH)
#define NBX 8
#define NBY 16
#define NBLK (NBX * NBY * 96)
#define C1F 1.0e-4f
#define C2F 9.0e-4f
#define H2P 28
#define PITCH 336       // staged row pitch in bytes (21 granules; 84 words -> 2-way banks, no swizzle)
#define FOFF 16384      // y-field byte offset (x field [0,16384), y [16384,32768))

typedef short s16x8 __attribute__((ext_vector_type(8)));
typedef float f32x4 __attribute__((ext_vector_type(4)));

// ---- helpers ----
__device__ __forceinline__ unsigned cvtpk(float a, float b) {   // lo=bf16(a), hi=bf16(b), RNE
    unsigned r;
    asm("v_cvt_pk_bf16_f32 %0, %1, %2" : "=v"(r) : "v"(a), "v"(b));
    return r;
}
__device__ __forceinline__ unsigned bf16_rne(float f) {
    unsigned u = __builtin_bit_cast(unsigned, f);
    return (u + 0x7FFFu + ((u >> 16) & 1u)) >> 16;
}
__device__ __forceinline__ float bf16_to_f(unsigned b) {
    return __builtin_bit_cast(float, b << 16);
}
__device__ __forceinline__ void gload16(const void* g, void* l) {
    __builtin_amdgcn_global_load_lds(
        (const __attribute__((address_space(1))) void*)g,
        (__attribute__((address_space(3))) void*)l,
        16, 0, 0);
}
__device__ __forceinline__ f32x4 spl4(float v) { f32x4 r = {v, v, v, v}; return r; }

// ---- setup: build per-lane MFMA weight fragments once (block-invariant) ----
__global__ void setup_kernel(uint4* __restrict__ wtab)
{
    const int lane = threadIdx.x;        // 0..63
    const int lane15 = lane & 15;
    const int g = lane >> 4;
    float w[11];
    float s = 0.f;
    for (int i = 0; i < 11; ++i) {
        const float c = (float)(i - 5);
        w[i] = expf(-(c * c) / 4.5f);
        s += w[i];
    }
    for (int i = 0; i < 11; ++i) w[i] /= s;

    s16x8 bwh, bwl, avh, avl;
    #pragma unroll
    for (int e = 0; e < 8; ++e) {
        const int k = 8 * g + e;
        // h-pass B (32x16): B[k][n] = w[k-n-3]  (slot origin c0-8; out col n = c0+16wv+n)
        const int th = k - lane15 - 3;
        const float wh = (th >= 0 && th <= 10) ? w[th] : 0.f;
        // v-pass A (16x32): A[i][k'] = w[k'-i]
        const int tv = k - lane15;
        const float wvv = (tv >= 0 && tv <= 10) ? w[tv] : 0.f;
        const unsigned h1 = bf16_rne(wh);
        const unsigned l1 = bf16_rne(wh - bf16_to_f(h1));
        bwh[e] = (short)h1; bwl[e] = (short)l1;
        const unsigned h2 = bf16_rne(wvv);
        const unsigned l2 = bf16_rne(wvv - bf16_to_f(h2));
        avh[e] = (short)h2; avl[e] = (short)l2;
    }
    wtab[lane * 4 + 0] = __builtin_bit_cast(uint4, bwh);
    wtab[lane * 4 + 1] = __builtin_bit_cast(uint4, bwl);
    wtab[lane * 4 + 2] = __builtin_bit_cast(uint4, avh);
    wtab[lane * 4 + 3] = __builtin_bit_cast(uint4, avl);
}

__global__ __launch_bounds__(256)
void ssim_l1_kernel(const float* __restrict__ warped,
                    const float* __restrict__ target,
                    const uint4* __restrict__ wtab,
                    float2* __restrict__ partial)
{
    // x rows 0..47 at [row*336], y at [16384 + row*336]; rows end 16128/32512, tails are pad.
    // After barrier2, words [0,7168) reused as H2. red at byte 32512 (y-field tail pad).
    __shared__ unsigned int LDSU[8192];   // 32768 B exactly -> 5 blocks/CU

    const int tid = threadIdx.x;
    const int lane = tid & 63;
    const int wv = tid >> 6;
    const int lane15 = lane & 15;
    const int g = (lane >> 4) & 3;
    const int c0 = blockIdx.x * 64;
    const int r0 = blockIdx.y * 32;
    const size_t base = (size_t)blockIdx.z * NPIX;
    char* LB = (char*)LDSU;

    // ---- stage raw x,y via async gload (linear dest, clamped source, no swizzle) ----
    {
        const char* xrow = (const char*)(warped + base);
        const char* yrow = (const char*)(target + base);
        const int cb0 = (c0 - 8) * 4;              // byte offset of slot 0 within an image row
        const int gb = 64 * wv + lane;             // granule index for i=0
        #pragma unroll
        for (int i = 0; i < 4; ++i) {
            const int ck = wv + 4 * i;             // 1KB chunk 0..15 (4 per wave per field)
            const unsigned G = (unsigned)(gb + 256 * i);      // global granule 0..1023
            const unsigned row = (G * 3121u) >> 16;           // G / 21, exact for G<1024
            const unsigned gl  = G - 21u * row;               // G % 21
            const int srow = min(max(r0 - 5 + (int)row, 0), IMH - 1);
            const int scolb = min(max(cb0 + (int)(gl << 4), 0), 2032);
            const size_t rb = (size_t)srow * (IMW * 4);
            gload16(xrow + rb + scolb, LB + 1024 * ck);
            gload16(yrow + rb + scolb, LB + FOFF + 1024 * ck);
        }
    }
    // ---- load weight fragments while loads fly ----
    const s16x8 BwH = __builtin_bit_cast(s16x8, wtab[lane * 4 + 0]);
    const s16x8 BwL = __builtin_bit_cast(s16x8, wtab[lane * 4 + 1]);
    const s16x8 AvH = __builtin_bit_cast(s16x8, wtab[lane * 4 + 2]);
    const s16x8 AvL = __builtin_bit_cast(s16x8, wtab[lane * 4 + 3]);

    __syncthreads();   // drains gload vmcnt

    // ---- masks ----
    const int s0 = 16 * wv + 8 * g;                 // first staging slot of this lane
    f32x4 cw0, cw1, mx0, mx1;
    #pragma unroll
    for (int e = 0; e < 4; ++e) {
        const int sA = s0 + e, sB = sA + 4;
        cw0[e] = (sA < 8 || sA > 71) ? 0.f : ((sA < 16 || sA >= 64) ? 1.f : 0.5f);
        cw1[e] = (sB < 8 || sB > 71) ? 0.f : ((sB < 16 || sB >= 64) ? 1.f : 0.5f);
        const int cA = c0 - 8 + sA, cB = c0 - 8 + sB;
        mx0[e] = ((unsigned)cA < (unsigned)IMW) ? 1.f : 0.f;
        mx1[e] = ((unsigned)cB < (unsigned)IMW) ? 1.f : 0.f;
    }
    const bool edge = (blockIdx.x == 0) || (blockIdx.x == NBX - 1) ||
                      (blockIdx.y == 0) || (blockIdx.y == NBY - 1);

    f32x4 l1v = spl4(0.f);
    f32x4 C[4][3];
    #pragma unroll
    for (int q = 0; q < 4; ++q)
        #pragma unroll
        for (int T = 0; T < 3; ++T)
            C[q][T] = spl4(0.f);

    // ---- h-pass ----
    const unsigned wb = (unsigned)(s0 * 4);         // byte offset in row (32B aligned)
    #pragma unroll
    for (int T = 0; T < 3; ++T) {
        const int rs = 16 * T + lane15;
        const char* p = LB + rs * PITCH + wb;
        f32x4 x0 = *(const f32x4*)p;
        f32x4 x1 = *(const f32x4*)(p + 16);
        f32x4 y0 = *(const f32x4*)(p + FOFF);
        f32x4 y1 = *(const f32x4*)(p + FOFF + 16);
        if (edge) {
            // zero-pad: out-of-image rows AND cols (exact SAME-padding semantics)
            const float rr = ((unsigned)(r0 - 5 + rs) < (unsigned)IMH) ? 1.f : 0.f;
            const f32x4 m0 = mx0 * spl4(rr);
            const f32x4 m1 = mx1 * spl4(rr);
            x0 *= m0; x1 *= m1; y0 *= m0; y1 *= m1;
        }

        // L1 (exact f32; output rows are slots 5..36, each counted once)
        {
            const float rmL1 = (T == 0) ? ((lane15 >= 5) ? 1.f : 0.f)
                             : (T == 1) ? 1.f
                             : ((lane15 <= 4) ? 1.f : 0.f);
            const f32x4 ad0 = __builtin_elementwise_abs(x0 - y0);
            const f32x4 ad1 = __builtin_elementwise_abs(x1 - y1);
            l1v = __builtin_elementwise_fma(cw0 * ad0 + cw1 * ad1, spl4(rmL1), l1v);
        }

        // quantity products (packed f32)
        const f32x4 q2a = __builtin_elementwise_fma(x0, x0, y0 * y0);
        const f32x4 q2b = __builtin_elementwise_fma(x1, x1, y1 * y1);
        const f32x4 q3a = x0 * y0;
        const f32x4 q3b = x1 * y1;

        uint4 A0u, A1u, A2u, A3u;
        A0u.x = cvtpk(x0[0], x0[1]); A0u.y = cvtpk(x0[2], x0[3]);
        A0u.z = cvtpk(x1[0], x1[1]); A0u.w = cvtpk(x1[2], x1[3]);
        A1u.x = cvtpk(y0[0], y0[1]); A1u.y = cvtpk(y0[2], y0[3]);
        A1u.z = cvtpk(y1[0], y1[1]); A1u.w = cvtpk(y1[2], y1[3]);
        A2u.x = cvtpk(q2a[0], q2a[1]); A2u.y = cvtpk(q2a[2], q2a[3]);
        A2u.z = cvtpk(q2b[0], q2b[1]); A2u.w = cvtpk(q2b[2], q2b[3]);
        A3u.x = cvtpk(q3a[0], q3a[1]); A3u.y = cvtpk(q3a[2], q3a[3]);
        A3u.z = cvtpk(q3b[0], q3b[1]); A3u.w = cvtpk(q3b[2], q3b[3]);

        const s16x8 A0 = __builtin_bit_cast(s16x8, A0u);
        const s16x8 A1 = __builtin_bit_cast(s16x8, A1u);
        const s16x8 A2 = __builtin_bit_cast(s16x8, A2u);
        const s16x8 A3 = __builtin_bit_cast(s16x8, A3u);

        C[0][T] = __builtin_amdgcn_mfma_f32_16x16x32_bf16(A0, BwH, C[0][T], 0, 0, 0);
        C[0][T] = __builtin_amdgcn_mfma_f32_16x16x32_bf16(A0, BwL, C[0][T], 0, 0, 0);
        C[1][T] = __builtin_amdgcn_mfma_f32_16x16x32_bf16(A1, BwH, C[1][T], 0, 0, 0);
        C[1][T] = __builtin_amdgcn_mfma_f32_16x16x32_bf16(A1, BwL, C[1][T], 0, 0, 0);
        C[2][T] = __builtin_amdgcn_mfma_f32_16x16x32_bf16(A2, BwH, C[2][T], 0, 0, 0);
        C[2][T] = __builtin_amdgcn_mfma_f32_16x16x32_bf16(A2, BwL, C[2][T], 0, 0, 0);
        C[3][T] = __builtin_amdgcn_mfma_f32_16x16x32_bf16(A3, BwH, C[3][T], 0, 0, 0);
        C[3][T] = __builtin_amdgcn_mfma_f32_16x16x32_bf16(A3, BwL, C[3][T], 0, 0, 0);
    }
    __syncthreads();   // all staging reads done before H2 overwrites the region

    // ---- repack C into H2 (wave-private band; bf16 pairs) ----
    #pragma unroll
    for (int q = 0; q < 4; ++q) {
        #pragma unroll
        for (int T = 0; T < 3; ++T) {
            uint2 p;
            p.x = cvtpk(C[q][T][0], C[q][T][1]);
            p.y = cvtpk(C[q][T][2], C[q][T][3]);
            *(uint2*)&LDSU[((wv * 4 + q) * 16 + lane15) * H2P + 8 * T + 2 * g] = p;
        }
    }

    // ---- v-pass + SSIM (packed f32 epilogue) ----
    f32x4 ssv = spl4(0.f);
    #pragma unroll
    for (int rbh = 0; rbh < 2; ++rbh) {
        f32x4 V[4];
        #pragma unroll
        for (int q = 0; q < 4; ++q) {
            const uint4 br = *(const uint4*)&LDSU[((wv * 4 + q) * 16 + lane15) * H2P + 8 * rbh + 4 * g];
            const s16x8 B = __builtin_bit_cast(s16x8, br);
            f32x4 acc = spl4(0.f);
            acc = __builtin_amdgcn_mfma_f32_16x16x32_bf16(AvH, B, acc, 0, 0, 0);
            acc = __builtin_amdgcn_mfma_f32_16x16x32_bf16(AvL, B, acc, 0, 0, 0);
            V[q] = acc;
        }
        const f32x4 mu12  = V[0] * V[1];
        const f32x4 mu1sq = V[0] * V[0];
        const f32x4 mu2sq = V[1] * V[1];
        const f32x4 s12   = V[3] - mu12;
        const f32x4 ssig  = V[2] - mu1sq - mu2sq;     // sigma1^2 + sigma2^2
        const f32x4 num = (spl4(2.f) * mu12 + spl4(C1F)) * (spl4(2.f) * s12 + spl4(C2F));
        const f32x4 den = (mu1sq + mu2sq + spl4(C1F)) * (ssig + spl4(C2F));
        f32x4 r;
        r[0] = __builtin_amdgcn_rcpf(den[0]);
        r[1] = __builtin_amdgcn_rcpf(den[1]);
        r[2] = __builtin_amdgcn_rcpf(den[2]);
        r[3] = __builtin_amdgcn_rcpf(den[3]);
        ssv = __builtin_elementwise_fma(num, r, ssv);
    }

    // ---- reductions ----
    float l1sum = (l1v[0] + l1v[1]) + (l1v[2] + l1v[3]);
    float ssum  = (ssv[0] + ssv[1]) + (ssv[2] + ssv[3]);
    #pragma unroll
    for (int off = 32; off > 0; off >>= 1) {
        l1sum += __shfl_down(l1sum, off);
        ssum  += __shfl_down(ssum,  off);
    }
    float* red = (float*)(LB + 32512);   // y-field tail pad, unused after staging
    if (lane == 0) { red[wv] = l1sum; red[4 + wv] = ssum; }
    __syncthreads();
    if (tid == 0) {
        const float L1 = red[0] + red[1] + red[2] + red[3];
        const float SS = red[4] + red[5] + red[6] + red[7];
        const int bid = (blockIdx.z * gridDim.y + blockIdx.y) * gridDim.x + blockIdx.x;
        partial[bid] = make_float2(L1, SS);
    }
}

__global__ __launch_bounds__(256)
void reduce_kernel(const float2* __restrict__ partial, float* __restrict__ out)
{
    double l1 = 0.0, ss = 0.0;
    for (int i = threadIdx.x; i < NBLK; i += 256) {
        const float2 p = partial[i];
        l1 += (double)p.x;
        ss += (double)p.y;
    }
    #pragma unroll
    for (int off = 32; off > 0; off >>= 1) {
        l1 += __shfl_down(l1, off);
        ss += __shfl_down(ss, off);
    }
    __shared__ double red[8];
    const int wv = threadIdx.x >> 6, lane = threadIdx.x & 63;
    if (lane == 0) { red[wv] = l1; red[4 + wv] = ss; }
    __syncthreads();
    if (threadIdx.x == 0) {
        const double n = 25165824.0;   // 32*3*512*512
        const double L1 = (red[0] + red[1] + red[2] + red[3]) / n;
        const double SS = (red[4] + red[5] + red[6] + red[7]) / n;
        out[0] = (float)(0.5 * L1 + 0.5 * (1.0 - SS));
    }
}

extern "C" void kernel_launch(void* const* d_in, const int* in_sizes, int n_in,
                              void* d_out, int out_size, void* d_ws, size_t ws_size,
                              hipStream_t stream)
{
    const float* warped = (const float*)d_in[0];
    const float* target = (const float*)d_in[1];
    float* out = (float*)d_out;
    uint4* wtab = (uint4*)d_ws;                            // 4 KB fragment table
    float2* partial = (float2*)((char*)d_ws + 4096);       // NBLK float2 partials

    hipLaunchKernelGGL(setup_kernel, dim3(1), dim3(64), 0, stream, wtab);
    hipLaunchKernelGGL(ssim_l1_kernel, dim3(NBX, NBY, 96), dim3(256), 0, stream,
                       warped, target, wtab, partial);
    hipLaunchKernelGGL(reduce_kernel, dim3(1), dim3(256), 0, stream, partial, out);
}